// Round 12
// baseline (368.962 us; speedup 1.0000x reference)
//
#include <hip/hip_runtime.h>

// CubePad: x [N*6, C, 256, 256] f32 -> out [N*6, C, 258, 258] f32, pad=1.
// Face order: 0=front, 1=right, 2=back, 3=left, 4=top, 5=down.
// Round-8 bulk/halo split + sched_barrier(0) between load loop and store loop
// to force 8 loads in flight per wave (compiler was collapsing to ~1; VGPR=24
// proved it). Bulk: blockIdx.x<9, 8 quads/thread, unconditional clamped
// unaligned 16B loads, purity-masked aligned 16B stores. Halo: blockIdx.x==9,
// ~510 non-pure quads/plane via verified value_at gather.

#define C_  64
#define H_  256
#define W_  256
#define HP  258
#define WP  258
#define FACE_STRIDE (C_ * H_ * W_)     // 4,194,304
#define PLANE_IN  (H_ * W_)            // 65,536
#define PLANE_OUT (HP * WP)            // 66,564 (16B-divisible)
#define QP_PLANE  (PLANE_OUT / 4)      // 16,641 quads per plane
#define TOTAL_IN  (12 * FACE_STRIDE)   // 50,331,648 elements

typedef float f4  __attribute__((ext_vector_type(4)));              // 16B aligned
typedef float f4u __attribute__((ext_vector_type(4), aligned(4)));  // 4B aligned

__device__ __forceinline__ float value_at(const float* __restrict__ base,
                                          int face, int h, int w) {
#define IN(f, hh, ww) base[(size_t)(f) * FACE_STRIDE + (hh) * W_ + (ww)]
  if (h >= 1 && h <= H_ && w >= 1 && w <= W_) return IN(face, h - 1, w - 1);
  if (h == 0) {                       // top plate (corners via clamp)
    int wi = w - 1; wi = wi < 0 ? 0 : (wi > 255 ? 255 : wi);
    switch (face) {
      case 0:  return IN(4, 255, wi);
      case 1:  return IN(4, 255 - wi, 255);
      case 2:  return IN(4, 0, 255 - wi);
      case 3:  return IN(4, wi, 0);
      case 4:  return IN(2, 0, 255 - wi);
      default: return IN(0, 255, wi);
    }
  }
  if (h == HP - 1) {                  // bottom plate (corners via clamp)
    int wi = w - 1; wi = wi < 0 ? 0 : (wi > 255 ? 255 : wi);
    switch (face) {
      case 0:  return IN(5, 0, wi);
      case 1:  return IN(5, wi, 255);
      case 2:  return IN(5, 255, 255 - wi);
      case 3:  return IN(5, 255 - wi, 0);
      case 4:  return IN(0, 0, wi);
      default: return IN(2, 255, 255 - wi);
    }
  }
  int hi = h - 1;                     // h in [1,256]
  if (w == 0) {                       // left column
    switch (face) {
      case 0:  return IN(3, hi, 255);
      case 1:  return IN(0, hi, 255);
      case 2:  return IN(1, hi, 255);
      case 3:  return IN(2, hi, 255);
      case 4:  return IN(3, 0, hi);
      default: return IN(3, 255, 255 - hi);
    }
  }
  // right column (w == 257)
  switch (face) {
    case 0:  return IN(1, hi, 0);
    case 1:  return IN(2, hi, 0);
    case 2:  return IN(3, hi, 0);
    case 3:  return IN(0, hi, 0);
    case 4:  return IN(1, 0, 255 - hi);
    default: return IN(1, 255, hi);
  }
#undef IN
}

__global__ __launch_bounds__(256) void cubepad_mlp_kernel(
    const float* __restrict__ x, float* __restrict__ out) {
  const int fgc = blockIdx.y;           // 0..767
  const int fg  = fgc >> 6;
  const int c   = fgc & 63;
  const int face = fg < 6 ? fg : fg - 6;
  const int nb   = fg < 6 ? 0 : 1;
  const int base_off = nb * 6 * FACE_STRIDE + c * PLANE_IN;
  const float* base = x + base_off;
  float* oplane = out + (size_t)fgc * PLANE_OUT;

  if (blockIdx.x < 9) {
    // ---------------- bulk: 8 quads per thread, deep MLP ----------------
    const int q0 = blockIdx.x * 2048 + threadIdx.x;
    f4 v[8];
#pragma unroll
    for (int k = 0; k < 8; ++k) {
      const int q = q0 + (k << 8);
      const unsigned p = (unsigned)q << 2;
      const unsigned h = p / 258u;        // magic-div
      const unsigned w = p - h * 258u;
      int off = base_off + face * FACE_STRIDE + ((int)h - 1) * W_ + ((int)w - 1);
      off = off < 0 ? 0 : off;
      off = off > (TOTAL_IN - 4) ? (TOTAL_IN - 4) : off;
      v[k] = *(const f4u*)(x + off);      // unconditional clamped 16B load
    }
    // Force all 8 loads issued before any store is scheduled: the compiler
    // was fusing load+store per quad (VGPR=24 => ~1 load in flight).
    __builtin_amdgcn_sched_barrier(0);
#pragma unroll
    for (int k = 0; k < 8; ++k) {
      const int q = q0 + (k << 8);
      const unsigned p = (unsigned)q << 2;
      const unsigned h = p / 258u;
      const unsigned w = p - h * 258u;
      const bool pure = (h >= 1u) & (h <= 256u) &
                        (w >= 1u) & (w <= 253u) & (q < QP_PLANE);
      if (pure) *(f4*)(oplane + ((size_t)q << 2)) = v[k];
    }
  } else {
    // ---------------- halo: non-pure quads via scalar gather --------------
    // slots: [0,65)   row-0 quads Q=j
    //        [65,130) row-257-region quads Q=16576+(j-65)
    //        [130,640) junctions r=2+(jj>>1), side=jj&1:
    //                  side0 Q=(258r-1)>>2; side1 (r even only) Q=(258r)>>2
    for (int it = 0; it < 3; ++it) {
      const int j = threadIdx.x + (it << 8);
      int Q = -1;
      if (j < 65) {
        Q = j;
      } else if (j < 130) {
        Q = 16576 + (j - 65);
      } else if (j < 640) {
        const int jj = j - 130;
        const int r = 2 + (jj >> 1);
        const int s = 258 * r;
        if ((jj & 1) == 0)       Q = (s - 1) >> 2;
        else if ((s & 3) == 0)   Q = s >> 2;      // r even: second quad
      }
      if (Q >= 0) {
        f4 v;
#pragma unroll
        for (int e = 0; e < 4; ++e) {
          const unsigned pe = ((unsigned)Q << 2) + e;
          const unsigned he = pe / 258u;
          const unsigned we = pe - he * 258u;
          v[e] = value_at(base, face, (int)he, (int)we);
        }
        *(f4*)(oplane + ((size_t)Q << 2)) = v;
      }
    }
  }
}

extern "C" void kernel_launch(void* const* d_in, const int* in_sizes, int n_in,
                              void* d_out, int out_size, void* d_ws, size_t ws_size,
                              hipStream_t stream) {
  const float* x = (const float*)d_in[0];
  float* out = (float*)d_out;
  dim3 grid(10, 768);   // x: 9 bulk blocks + 1 halo block per plane
  cubepad_mlp_kernel<<<grid, 256, 0, stream>>>(x, out);
}